// Round 11
// baseline (150.033 us; speedup 1.0000x reference)
//
#include <hip/hip_runtime.h>

// GCN forward on MI355X (gfx950).
// R11: (1) bucket passes re-parallelized — EPB 1024 / RB 64 gives 782
// blocks (~3/CU) instead of 196 (<1/CU); R10 profile showed mega1=43us,
// occupancy 11%: the 196-block bscatter's ds_add_rtn rank chains had no
// TLP to hide under. (2) split-dim dense [2][N][32]: 3.2MB half fits the
// 4MB per-XCD L2, making the gather's random reads L2-hits; wave = 2
// edges x 32 dims, __shfl_xor(32) combine. 6 dispatches.

#define N_NODES 50000
#define N_EDGES 800000
#define IN_DIM  128
#define HID_DIM 64
#define OUT_DIM 64

#define RB   64                       // rows per bucket
#define NB   ((N_NODES + RB - 1) / RB)            // 782
#define EPB  1024                     // edges per bscatter block
#define NBLK_E ((N_EDGES + EPB - 1) / EPB)        // 782
#define BCAP 1280                     // padded bucket region; E=1023, sigma~32
#define GEMM1_GRID ((N_NODES + 31) / 32)          // 1563
#define GRID_HALF (N_NODES / 4)                   // 12500 gather blocks/half
#define HALF_ELEMS ((size_t)N_NODES * 32)

typedef __attribute__((ext_vector_type(8))) short bf16x8;
typedef __attribute__((ext_vector_type(4))) float f32x4;

__device__ inline unsigned short f2bf(float x) {   // RNE fp32 -> bf16
    unsigned u = __float_as_uint(x);
    return (unsigned short)((u + 0x7FFFu + ((u >> 16) & 1u)) >> 16);
}
__device__ inline float bf2f(unsigned v) {
    return __uint_as_float(v << 16);
}

// ---------------- prep: weight transpose+bf16 convert, bcur zero ------
__global__ __launch_bounds__(256) void k_prep(
    const float* __restrict__ W1, unsigned short* __restrict__ Wt1,
    const float* __restrict__ W2, unsigned short* __restrict__ Wt2,
    int* __restrict__ bcur)
{
    int b = blockIdx.x, t = threadIdx.x;
    if (b < 32) {                       // IN_DIM*HID_DIM = 8192 = 32*256
        int e = b * 256 + t;
        int c = e / IN_DIM, k = e % IN_DIM;
        Wt1[c * IN_DIM + k] = f2bf(W1[k * HID_DIM + c]);
    } else if (b < 48) {                // HID_DIM*OUT_DIM = 4096 = 16*256
        int e2 = (b - 32) * 256 + t;
        int c = e2 / HID_DIM, k = e2 % HID_DIM;
        Wt2[c * HID_DIM + k] = f2bf(W2[k * OUT_DIM + c]);
    } else {
        for (int i = t; i < NB; i += 256) bcur[i] = 0;
    }
}

// ---------------- MFMA GEMM body (32 rows/block, 4 waves) -------------
// LDS tiles XOR-swizzled (byte ^= (row&7)<<4). OUTPUT is split-half
// layout: out[half][row][d], half = col/32. For IN_BF16 (layer 2) the
// A input is ALSO split-half (agg1).
template <int K, bool IN_BF16>
__device__ __forceinline__ void gemm_body(
    unsigned short* __restrict__ Al, unsigned short* __restrict__ Bl,
    const void* __restrict__ Xv, const unsigned short* __restrict__ Wt,
    unsigned short* __restrict__ out, int bid, int t)
{
    int m0 = bid * 32;
    #pragma unroll
    for (int i = 0; i < K / 32; ++i) {
        int u4 = i * 256 + t;                 // uint4 index
        int col = (u4 * 8) / K, k = (u4 * 8) % K;
        uint4 w = ((const uint4*)Wt)[u4];
        int byte = (col * K + k) * 2;
        byte ^= ((col & 7) << 4);
        *(uint4*)((char*)Bl + byte) = w;
    }
    if (IN_BF16) {
        // A from split-half bf16 [2][N][32]; K = 64
        const unsigned short* X = (const unsigned short*)Xv;
        int row = t / (K / 8), k = (t % (K / 8)) * 8;
        int grow = m0 + row;
        int hf = k >> 5;
        uint4 v = make_uint4(0, 0, 0, 0);
        if (grow < N_NODES)
            v = *(const uint4*)(X + (size_t)hf * HALF_ELEMS
                                + (size_t)grow * 32 + (k & 31));
        int byte = (row * K + k) * 2;
        byte ^= ((row & 7) << 4);
        *(uint4*)((char*)Al + byte) = v;
    } else {
        const float* X = (const float*)Xv;
        #pragma unroll
        for (int i = 0; i < K / 64; ++i) {
            int f8 = i * 256 + t;             // 8-float group
            int row = (f8 * 8) / K, k = (f8 * 8) % K;
            int grow = m0 + row;
            float4 xa = make_float4(0.f, 0.f, 0.f, 0.f), xb = xa;
            if (grow < N_NODES) {
                const float4* src = (const float4*)(X + (size_t)grow * K + k);
                xa = src[0];
                xb = src[1];
            }
            uint4 v;
            v.x = (unsigned)f2bf(xa.x) | ((unsigned)f2bf(xa.y) << 16);
            v.y = (unsigned)f2bf(xa.z) | ((unsigned)f2bf(xa.w) << 16);
            v.z = (unsigned)f2bf(xb.x) | ((unsigned)f2bf(xb.y) << 16);
            v.w = (unsigned)f2bf(xb.z) | ((unsigned)f2bf(xb.w) << 16);
            int byte = (row * K + k) * 2;
            byte ^= ((row & 7) << 4);
            *(uint4*)((char*)Al + byte) = v;
        }
    }
    __syncthreads();

    int w = t >> 6, l = t & 63;
    int lr0 = (w & 1) * 16;
    int c0  = (w >> 1) * 32;                  // cols [c0, c0+32) = half w>>1
    int lrow = lr0 + (l & 15);
    int kb = (l >> 4) * 8;
    int col0 = c0 + (l & 15), col1 = col0 + 16;
    f32x4 acc0 = {0.f, 0.f, 0.f, 0.f}, acc1 = {0.f, 0.f, 0.f, 0.f};
    #pragma unroll
    for (int kc = 0; kc < K / 32; ++kc) {
        int ka = kc * 32 + kb;
        int ab = (lrow * K + ka) * 2;  ab ^= ((lrow & 7) << 4);
        int bb0 = (col0 * K + ka) * 2; bb0 ^= ((col0 & 7) << 4);
        int bb1 = (col1 * K + ka) * 2; bb1 ^= ((col1 & 7) << 4);
        bf16x8 a  = *(const bf16x8*)((const char*)Al + ab);
        bf16x8 b0 = *(const bf16x8*)((const char*)Bl + bb0);
        bf16x8 b1 = *(const bf16x8*)((const char*)Bl + bb1);
        acc0 = __builtin_amdgcn_mfma_f32_16x16x32_bf16(a, b0, acc0, 0, 0, 0);
        acc1 = __builtin_amdgcn_mfma_f32_16x16x32_bf16(a, b1, acc1, 0, 0, 0);
    }
    // split-half store: half = w>>1, in-half cols (l&15) and (l&15)+16
    unsigned short* oh = out + (size_t)(w >> 1) * HALF_ELEMS;
    int lc0 = l & 15;
    int grow0 = m0 + lr0 + (l >> 4) * 4;
    #pragma unroll
    for (int j = 0; j < 4; ++j) {
        int gr = grow0 + j;
        if (gr < N_NODES) {
            oh[(size_t)gr * 32 + lc0]      = f2bf(acc0[j]);
            oh[(size_t)gr * 32 + lc0 + 16] = f2bf(acc1[j]);
        }
    }
}

// ---------------- mega1: GEMM1 (blocks < GEMM1_GRID) || bscatter ------
__global__ __launch_bounds__(256) void k_mega1(
    const float* __restrict__ X, const unsigned short* __restrict__ Wt1,
    unsigned short* __restrict__ support,
    const int* __restrict__ erow, const int* __restrict__ ecol,
    const float* __restrict__ eval_, int* __restrict__ bcur,
    uint2* __restrict__ bucketed)
{
    __shared__ __align__(16) unsigned char smem[24576];
    int t = threadIdx.x;
    if (blockIdx.x < GEMM1_GRID) {
        gemm_body<IN_DIM, false>((unsigned short*)smem,
                                 (unsigned short*)(smem + 8192),
                                 X, Wt1, support, blockIdx.x, t);
        return;
    }
    // ---- bscatter: 1024 edges/block into padded bucket regions ----
    // word0 = col (16b) | rowlow (6b) << 16; word1 = val bits.
    int* lc    = (int*)smem;           // NB ints
    int* lbase = lc + NB;
    int blk = blockIdx.x - GEMM1_GRID;
    for (int i = t; i < NB; i += 256) lc[i] = 0;
    __syncthreads();
    int base = blk * EPB;
    int bkt[4], rnk[4];
    #pragma unroll
    for (int i = 0; i < 4; ++i) {
        int e = base + i * 256 + t;
        bkt[i] = -1;
        if (e < N_EDGES) {
            bkt[i] = erow[e] >> 6;
            rnk[i] = atomicAdd(&lc[bkt[i]], 1);
        }
    }
    __syncthreads();
    for (int i = t; i < NB; i += 256)
        lbase[i] = lc[i] ? atomicAdd(&bcur[i], lc[i]) : 0;
    __syncthreads();
    #pragma unroll
    for (int i = 0; i < 4; ++i) {
        int e = base + i * 256 + t;
        if (bkt[i] >= 0) {
            unsigned r = (unsigned)erow[e];
            unsigned w0 = (unsigned)ecol[e] | ((r & 63u) << 16);
            bucketed[(size_t)bkt[i] * BCAP + lbase[bkt[i]] + rnk[i]] =
                make_uint2(w0, __float_as_uint(eval_[e]));
        }
    }
}

// ---------------- pass B: one block per 64-row bucket -----------------
// LDS-cache the bucket's ~1024 edges; count -> wave-0 shuffle scan ->
// offs2[row]=(start,end) -> row-sorted scatter into pairs.
__global__ __launch_bounds__(256) void k_bfinal(
    const int* __restrict__ bcur, const uint2* __restrict__ bucketed,
    uint2* __restrict__ pairs, int2* __restrict__ offs2)
{
    __shared__ uint2 ebuf[BCAP];        // 10 KB
    __shared__ int rcnt[RB];
    __shared__ int rcur[RB];
    int t = threadIdx.x, b = blockIdx.x;
    int ne = bcur[b];
    int base0 = b * BCAP;
    if (t < RB) rcnt[t] = 0;
    __syncthreads();
    for (int i = t; i < ne; i += 256) {
        uint2 p = bucketed[(size_t)base0 + i];
        ebuf[i] = p;
        atomicAdd(&rcnt[(p.x >> 16) & 63], 1);
    }
    __syncthreads();
    if (t < RB) {                        // wave 0: 64-lane shuffle scan
        int v = rcnt[t];
        int s = v;
        #pragma unroll
        for (int off = 1; off < RB; off <<= 1) {
            int o = __shfl_up(s, off, 64);
            if (t >= off) s += o;
        }
        int start = base0 + s - v;
        int gr = b * RB + t;
        if (gr < N_NODES) offs2[gr] = make_int2(start, start + v);
        rcur[t] = start;
    }
    __syncthreads();
    for (int i = t; i < ne; i += 256) {
        uint2 p = ebuf[i];
        int pos = atomicAdd(&rcur[(p.x >> 16) & 63], 1);
        pairs[pos] = make_uint2(p.x & 0xFFFFu, p.y);
    }
}

// ---------------- gather SpMM: split-half dense, 2 edges/wave-iter ----
// Block = 4 waves = 4 rows, one 32-dim half (3.2MB -> L2-resident).
// Lane = (sub = l>>5, d = l&31): sub picks even/odd edge, cross-lane
// __shfl_xor(32) combines. 8 edges per unrolled iter, 4 loads/lane.
template <bool APPLY_RELU, bool OUT_BF16>
__global__ __launch_bounds__(256) void k_gather(
    const int2* __restrict__ offs2, const uint2* __restrict__ pairs,
    const unsigned short* __restrict__ dense, const float* __restrict__ bias,
    void* __restrict__ outp)
{
    int t = threadIdx.x;
    int half = (blockIdx.x >= GRID_HALF) ? 1 : 0;
    int rb = blockIdx.x - half * GRID_HALF;
    int r = __builtin_amdgcn_readfirstlane(rb * 4 + (t >> 6));
    int l = t & 63;
    int sub = l >> 5, d = l & 31;
    const unsigned short* dh = dense + (size_t)half * HALF_ELEMS;
    int2 oe = offs2[r];
    int e0 = oe.x, e1 = oe.y;
    float a[4];
    a[0] = (sub == 0) ? bias[half * 32 + d] : 0.f;
    a[1] = a[2] = a[3] = 0.f;
    int e = e0;
    for (; e + 8 <= e1; e += 8) {
        uint2 p[4];
        #pragma unroll
        for (int i = 0; i < 4; ++i) p[i] = pairs[e + 2 * i + sub];
        unsigned v[4];
        #pragma unroll
        for (int i = 0; i < 4; ++i)
            v[i] = dh[(size_t)(p[i].x & 0xFFFFu) * 32u + d];
        #pragma unroll
        for (int i = 0; i < 4; ++i)
            a[i] = fmaf(__uint_as_float(p[i].y), bf2f(v[i]), a[i]);
    }
    for (; e < e1; e += 2) {
        int idx = e + sub;
        if (idx < e1) {
            uint2 p = pairs[idx];
            a[0] = fmaf(__uint_as_float(p.y),
                        bf2f(dh[(size_t)(p.x & 0xFFFFu) * 32u + d]), a[0]);
        }
    }
    float s = (a[0] + a[1]) + (a[2] + a[3]);
    s += __shfl_xor(s, 32, 64);
    if (APPLY_RELU) s = fmaxf(s, 0.f);
    if (sub == 0) {
        if (OUT_BF16)   // split-half bf16 (consumed by gemm2)
            ((unsigned short*)outp)[(size_t)half * HALF_ELEMS
                                    + (size_t)r * 32 + d] = f2bf(s);
        else            // final fp32 [N][64]
            ((float*)outp)[(size_t)r * 64 + half * 32 + d] = s;
    }
}

// ---------------- GEMM2 standalone (K=64, split bf16 in/out) ----------
__global__ __launch_bounds__(256) void k_gemm2(
    const unsigned short* __restrict__ X, const unsigned short* __restrict__ Wt,
    unsigned short* __restrict__ out)
{
    __shared__ unsigned short Al[32 * HID_DIM];
    __shared__ unsigned short Bl[64 * HID_DIM];
    gemm_body<HID_DIM, true>(Al, Bl, X, Wt, out, blockIdx.x, threadIdx.x);
}

extern "C" void kernel_launch(void* const* d_in, const int* in_sizes, int n_in,
                              void* d_out, int out_size, void* d_ws, size_t ws_size,
                              hipStream_t stream)
{
    const float* x     = (const float*)d_in[0];
    const int*   erow  = (const int*)d_in[1];
    const int*   ecol  = (const int*)d_in[2];
    const float* eval_ = (const float*)d_in[3];
    const float* W1    = (const float*)d_in[4];
    const float* b1    = (const float*)d_in[5];
    const float* W2    = (const float*)d_in[6];
    const float* b2    = (const float*)d_in[7];
    float* out = (float*)d_out;

    // ws (~29.5 MB): pairs 8.0MB | bucketed 8.0MB | support bf16 6.4MB
    // (split [2][N][32]) | agg1 bf16 6.4MB (split) | Wt1 | Wt2 | bcur | offs2
    uint2* pairs    = (uint2*)d_ws;
    uint2* bucketed = pairs + (size_t)NB * BCAP;
    unsigned short* support = (unsigned short*)(bucketed + (size_t)NB * BCAP);
    unsigned short* agg1 = support + 2 * HALF_ELEMS;
    unsigned short* Wt1 = agg1 + 2 * HALF_ELEMS;
    unsigned short* Wt2 = Wt1 + IN_DIM * HID_DIM;
    int*  bcur  = (int*)(Wt2 + HID_DIM * OUT_DIM);
    int2* offs2 = (int2*)(bcur + NB + 2);      // 8B-aligned

    // 6 dispatches
    k_prep<<<49, 256, 0, stream>>>(W1, Wt1, W2, Wt2, bcur);
    k_mega1<<<GEMM1_GRID + NBLK_E, 256, 0, stream>>>(
        x, Wt1, support, erow, ecol, eval_, bcur, bucketed);
    k_bfinal<<<NB, 256, 0, stream>>>(bcur, bucketed, pairs, offs2);
    k_gather<true, true><<<2 * GRID_HALF, 256, 0, stream>>>(
        offs2, pairs, support, b1, agg1);
    k_gemm2<<<GEMM1_GRID, 256, 0, stream>>>(agg1, Wt2, support);
    k_gather<false, false><<<2 * GRID_HALF, 256, 0, stream>>>(
        offs2, pairs, support, b2, out);
}

// Round 12
// 100.754 us; speedup vs baseline: 1.4891x; 1.4891x over previous
//
#include <hip/hip_runtime.h>

// GCN forward on MI355X (gfx950).
// R12: recombine proven parts — R8's gather (full-row [N][64] bf16, 8-way
// unroll = 8 loads in flight; the R11 split-dim variant halved MLP and
// doubled the pairs stream, 2.7x regression) + R11's parallel bucketing
// (RB=64/EPB=1024, ~3 blocks/CU) + GEMM1||bscatter fusion. 6 dispatches.

#define N_NODES 50000
#define N_EDGES 800000
#define IN_DIM  128
#define HID_DIM 64
#define OUT_DIM 64

#define RB   64                       // rows per bucket
#define NB   ((N_NODES + RB - 1) / RB)            // 782
#define EPB  1024                     // edges per bscatter block
#define NBLK_E ((N_EDGES + EPB - 1) / EPB)        // 782
#define BCAP 1280                     // padded bucket region; E=1023, sigma~32
#define GEMM1_GRID ((N_NODES + 31) / 32)          // 1563

typedef __attribute__((ext_vector_type(8))) short bf16x8;
typedef __attribute__((ext_vector_type(4))) float f32x4;

__device__ inline unsigned short f2bf(float x) {   // RNE fp32 -> bf16
    unsigned u = __float_as_uint(x);
    return (unsigned short)((u + 0x7FFFu + ((u >> 16) & 1u)) >> 16);
}
__device__ inline float bf2f(unsigned v) {
    return __uint_as_float(v << 16);
}

// ---------------- prep: weight transpose+bf16 convert, bcur zero ------
__global__ __launch_bounds__(256) void k_prep(
    const float* __restrict__ W1, unsigned short* __restrict__ Wt1,
    const float* __restrict__ W2, unsigned short* __restrict__ Wt2,
    int* __restrict__ bcur)
{
    int b = blockIdx.x, t = threadIdx.x;
    if (b < 32) {                       // IN_DIM*HID_DIM = 8192 = 32*256
        int e = b * 256 + t;
        int c = e / IN_DIM, k = e % IN_DIM;
        Wt1[c * IN_DIM + k] = f2bf(W1[k * HID_DIM + c]);
    } else if (b < 48) {                // HID_DIM*OUT_DIM = 4096 = 16*256
        int e2 = (b - 32) * 256 + t;
        int c = e2 / HID_DIM, k = e2 % HID_DIM;
        Wt2[c * HID_DIM + k] = f2bf(W2[k * OUT_DIM + c]);
    } else {
        for (int i = t; i < NB; i += 256) bcur[i] = 0;
    }
}

// ---------------- MFMA GEMM body (32 rows/block, 4 waves) -------------
// Both LDS tiles XOR-swizzled (byte ^= (row&7)<<4). Linear [N][64] bf16 out.
template <int K, bool IN_BF16>
__device__ __forceinline__ void gemm_body(
    unsigned short* __restrict__ Al, unsigned short* __restrict__ Bl,
    const void* __restrict__ Xv, const unsigned short* __restrict__ Wt,
    unsigned short* __restrict__ out, int bid, int t)
{
    int m0 = bid * 32;
    #pragma unroll
    for (int i = 0; i < K / 32; ++i) {
        int u4 = i * 256 + t;                 // uint4 index
        int col = (u4 * 8) / K, k = (u4 * 8) % K;
        uint4 w = ((const uint4*)Wt)[u4];
        int byte = (col * K + k) * 2;
        byte ^= ((col & 7) << 4);
        *(uint4*)((char*)Bl + byte) = w;
    }
    if (IN_BF16) {
        const unsigned short* X = (const unsigned short*)Xv;
        int row = t / (K / 8), k = (t % (K / 8)) * 8;
        int grow = m0 + row;
        uint4 v = make_uint4(0, 0, 0, 0);
        if (grow < N_NODES)
            v = *(const uint4*)(X + (size_t)grow * K + k);
        int byte = (row * K + k) * 2;
        byte ^= ((row & 7) << 4);
        *(uint4*)((char*)Al + byte) = v;
    } else {
        const float* X = (const float*)Xv;
        #pragma unroll
        for (int i = 0; i < K / 64; ++i) {
            int f8 = i * 256 + t;             // 8-float group
            int row = (f8 * 8) / K, k = (f8 * 8) % K;
            int grow = m0 + row;
            float4 xa = make_float4(0.f, 0.f, 0.f, 0.f), xb = xa;
            if (grow < N_NODES) {
                const float4* src = (const float4*)(X + (size_t)grow * K + k);
                xa = src[0];
                xb = src[1];
            }
            uint4 v;
            v.x = (unsigned)f2bf(xa.x) | ((unsigned)f2bf(xa.y) << 16);
            v.y = (unsigned)f2bf(xa.z) | ((unsigned)f2bf(xa.w) << 16);
            v.z = (unsigned)f2bf(xb.x) | ((unsigned)f2bf(xb.y) << 16);
            v.w = (unsigned)f2bf(xb.z) | ((unsigned)f2bf(xb.w) << 16);
            int byte = (row * K + k) * 2;
            byte ^= ((row & 7) << 4);
            *(uint4*)((char*)Al + byte) = v;
        }
    }
    __syncthreads();

    int w = t >> 6, l = t & 63;
    int lr0 = (w & 1) * 16;
    int c0  = (w >> 1) * 32;
    int lrow = lr0 + (l & 15);
    int kb = (l >> 4) * 8;
    int col0 = c0 + (l & 15), col1 = col0 + 16;
    f32x4 acc0 = {0.f, 0.f, 0.f, 0.f}, acc1 = {0.f, 0.f, 0.f, 0.f};
    #pragma unroll
    for (int kc = 0; kc < K / 32; ++kc) {
        int ka = kc * 32 + kb;
        int ab = (lrow * K + ka) * 2;  ab ^= ((lrow & 7) << 4);
        int bb0 = (col0 * K + ka) * 2; bb0 ^= ((col0 & 7) << 4);
        int bb1 = (col1 * K + ka) * 2; bb1 ^= ((col1 & 7) << 4);
        bf16x8 a  = *(const bf16x8*)((const char*)Al + ab);
        bf16x8 b0 = *(const bf16x8*)((const char*)Bl + bb0);
        bf16x8 b1 = *(const bf16x8*)((const char*)Bl + bb1);
        acc0 = __builtin_amdgcn_mfma_f32_16x16x32_bf16(a, b0, acc0, 0, 0, 0);
        acc1 = __builtin_amdgcn_mfma_f32_16x16x32_bf16(a, b1, acc1, 0, 0, 0);
    }
    int grow0 = m0 + lr0 + (l >> 4) * 4;
    #pragma unroll
    for (int j = 0; j < 4; ++j) {
        int gr = grow0 + j;
        if (gr < N_NODES) {
            out[(size_t)gr * 64 + col0] = f2bf(acc0[j]);
            out[(size_t)gr * 64 + col1] = f2bf(acc1[j]);
        }
    }
}

// ---------------- mega1: GEMM1 (blocks < GEMM1_GRID) || bscatter ------
__global__ __launch_bounds__(256) void k_mega1(
    const float* __restrict__ X, const unsigned short* __restrict__ Wt1,
    unsigned short* __restrict__ support,
    const int* __restrict__ erow, const int* __restrict__ ecol,
    const float* __restrict__ eval_, int* __restrict__ bcur,
    uint2* __restrict__ bucketed)
{
    __shared__ __align__(16) unsigned char smem[24576];
    int t = threadIdx.x;
    if (blockIdx.x < GEMM1_GRID) {
        gemm_body<IN_DIM, false>((unsigned short*)smem,
                                 (unsigned short*)(smem + 8192),
                                 X, Wt1, support, blockIdx.x, t);
        return;
    }
    // ---- bscatter: 1024 edges/block into padded bucket regions ----
    // word0 = col (16b) | rowlow (6b) << 16; word1 = val bits.
    int* lc    = (int*)smem;           // NB ints
    int* lbase = lc + NB;
    int blk = blockIdx.x - GEMM1_GRID;
    for (int i = t; i < NB; i += 256) lc[i] = 0;
    __syncthreads();
    int base = blk * EPB;
    int bkt[4], rnk[4];
    #pragma unroll
    for (int i = 0; i < 4; ++i) {
        int e = base + i * 256 + t;
        bkt[i] = -1;
        if (e < N_EDGES) {
            bkt[i] = erow[e] >> 6;
            rnk[i] = atomicAdd(&lc[bkt[i]], 1);
        }
    }
    __syncthreads();
    for (int i = t; i < NB; i += 256)
        lbase[i] = lc[i] ? atomicAdd(&bcur[i], lc[i]) : 0;
    __syncthreads();
    #pragma unroll
    for (int i = 0; i < 4; ++i) {
        int e = base + i * 256 + t;
        if (bkt[i] >= 0) {
            unsigned r = (unsigned)erow[e];
            unsigned w0 = (unsigned)ecol[e] | ((r & 63u) << 16);
            bucketed[(size_t)bkt[i] * BCAP + lbase[bkt[i]] + rnk[i]] =
                make_uint2(w0, __float_as_uint(eval_[e]));
        }
    }
}

// ---------------- pass B: one block per 64-row bucket -----------------
// LDS-cache the bucket's ~1024 edges; count -> wave-0 shuffle scan ->
// offs2[row]=(start,end) -> row-sorted scatter into pairs.
__global__ __launch_bounds__(256) void k_bfinal(
    const int* __restrict__ bcur, const uint2* __restrict__ bucketed,
    uint2* __restrict__ pairs, int2* __restrict__ offs2)
{
    __shared__ uint2 ebuf[BCAP];        // 10 KB
    __shared__ int rcnt[RB];
    __shared__ int rcur[RB];
    int t = threadIdx.x, b = blockIdx.x;
    int ne = bcur[b];
    int base0 = b * BCAP;
    if (t < RB) rcnt[t] = 0;
    __syncthreads();
    for (int i = t; i < ne; i += 256) {
        uint2 p = bucketed[(size_t)base0 + i];
        ebuf[i] = p;
        atomicAdd(&rcnt[(p.x >> 16) & 63], 1);
    }
    __syncthreads();
    if (t < RB) {                        // wave 0: 64-lane shuffle scan
        int v = rcnt[t];
        int s = v;
        #pragma unroll
        for (int off = 1; off < RB; off <<= 1) {
            int o = __shfl_up(s, off, 64);
            if (t >= off) s += o;
        }
        int start = base0 + s - v;
        int gr = b * RB + t;
        if (gr < N_NODES) offs2[gr] = make_int2(start, start + v);
        rcur[t] = start;
    }
    __syncthreads();
    for (int i = t; i < ne; i += 256) {
        uint2 p = ebuf[i];
        int pos = atomicAdd(&rcur[(p.x >> 16) & 63], 1);
        pairs[pos] = make_uint2(p.x & 0xFFFFu, p.y);
    }
}

// ---------------- gather SpMM: bf16 dense [N][64], 8-way unroll -------
// One wave per row, lane = feature dim; 8 independent accumulators keep
// 8 random 128B dense reads in flight. r/e0/e1 wave-uniform (scalar).
template <bool APPLY_RELU, bool OUT_BF16>
__global__ __launch_bounds__(256) void k_gather(
    const int2* __restrict__ offs2, const uint2* __restrict__ pairs,
    const unsigned short* __restrict__ dense, const float* __restrict__ bias,
    void* __restrict__ outp)
{
    int t = threadIdx.x;
    int r = __builtin_amdgcn_readfirstlane(blockIdx.x * 4 + (t >> 6));
    int d = t & 63;
    int2 oe = offs2[r];
    int e0 = oe.x, e1 = oe.y;
    float a[8];
    a[0] = bias[d];
    #pragma unroll
    for (int i = 1; i < 8; ++i) a[i] = 0.f;
    int e = e0;
    for (; e + 8 <= e1; e += 8) {
        uint2 p[8];
        #pragma unroll
        for (int i = 0; i < 8; ++i) p[i] = pairs[e + i];
        unsigned v[8];
        #pragma unroll
        for (int i = 0; i < 8; ++i) v[i] = dense[(size_t)p[i].x * 64u + d];
        #pragma unroll
        for (int i = 0; i < 8; ++i)
            a[i] = fmaf(__uint_as_float(p[i].y), bf2f(v[i]), a[i]);
    }
    if (e + 4 <= e1) {
        uint2 p[4];
        #pragma unroll
        for (int i = 0; i < 4; ++i) p[i] = pairs[e + i];
        unsigned v[4];
        #pragma unroll
        for (int i = 0; i < 4; ++i) v[i] = dense[(size_t)p[i].x * 64u + d];
        #pragma unroll
        for (int i = 0; i < 4; ++i)
            a[i] = fmaf(__uint_as_float(p[i].y), bf2f(v[i]), a[i]);
        e += 4;
    }
    for (; e < e1; ++e) {
        uint2 p = pairs[e];
        a[0] = fmaf(__uint_as_float(p.y),
                    bf2f(dense[(size_t)p.x * 64u + d]), a[0]);
    }
    float acc = ((a[0] + a[1]) + (a[2] + a[3])) +
                ((a[4] + a[5]) + (a[6] + a[7]));
    if (APPLY_RELU) acc = fmaxf(acc, 0.f);
    if (OUT_BF16)
        ((unsigned short*)outp)[(size_t)r * 64 + d] = f2bf(acc);
    else
        ((float*)outp)[(size_t)r * 64 + d] = acc;
}

// ---------------- GEMM2 standalone (K=64, bf16 in) --------------------
__global__ __launch_bounds__(256) void k_gemm2(
    const unsigned short* __restrict__ X, const unsigned short* __restrict__ Wt,
    unsigned short* __restrict__ out)
{
    __shared__ unsigned short Al[32 * HID_DIM];
    __shared__ unsigned short Bl[64 * HID_DIM];
    gemm_body<HID_DIM, true>(Al, Bl, X, Wt, out, blockIdx.x, threadIdx.x);
}

extern "C" void kernel_launch(void* const* d_in, const int* in_sizes, int n_in,
                              void* d_out, int out_size, void* d_ws, size_t ws_size,
                              hipStream_t stream)
{
    const float* x     = (const float*)d_in[0];
    const int*   erow  = (const int*)d_in[1];
    const int*   ecol  = (const int*)d_in[2];
    const float* eval_ = (const float*)d_in[3];
    const float* W1    = (const float*)d_in[4];
    const float* b1    = (const float*)d_in[5];
    const float* W2    = (const float*)d_in[6];
    const float* b2    = (const float*)d_in[7];
    float* out = (float*)d_out;

    // ws (~29.5 MB): pairs 8.0MB | bucketed 8.0MB | support bf16 6.4MB |
    // agg1 bf16 6.4MB | Wt1 | Wt2 | bcur | offs2
    uint2* pairs    = (uint2*)d_ws;
    uint2* bucketed = pairs + (size_t)NB * BCAP;
    unsigned short* support = (unsigned short*)(bucketed + (size_t)NB * BCAP);
    unsigned short* agg1 = support + (size_t)N_NODES * 64;
    unsigned short* Wt1 = agg1 + (size_t)N_NODES * 64;
    unsigned short* Wt2 = Wt1 + IN_DIM * HID_DIM;
    int*  bcur  = (int*)(Wt2 + HID_DIM * OUT_DIM);
    int2* offs2 = (int2*)(bcur + NB);          // NB=782 even -> 8B-aligned

    const int row_grid = N_NODES / 4;          // 12500 (gather)

    // 6 dispatches
    k_prep<<<49, 256, 0, stream>>>(W1, Wt1, W2, Wt2, bcur);
    k_mega1<<<GEMM1_GRID + NBLK_E, 256, 0, stream>>>(
        x, Wt1, support, erow, ecol, eval_, bcur, bucketed);
    k_bfinal<<<NB, 256, 0, stream>>>(bcur, bucketed, pairs, offs2);
    k_gather<true, true><<<row_grid, 256, 0, stream>>>(
        offs2, pairs, support, b1, agg1);
    k_gemm2<<<GEMM1_GRID, 256, 0, stream>>>(agg1, Wt2, support);
    k_gather<false, false><<<row_grid, 256, 0, stream>>>(
        offs2, pairs, support, b2, out);
}

// Round 13
// 96.242 us; speedup vs baseline: 1.5589x; 1.0469x over previous
//
#include <hip/hip_runtime.h>

// GCN forward on MI355X (gfx950).
// R13: bscatter rewritten — R4/R10/R12 all hit the same ~45us wall for
// 800k fully-scattered 8B global stores (each wave store = 64 line-dirtying
// transactions; WRITE amplification 3.4x). Fix: sort the block's 4096
// edges by bucket in LDS (rank atomics + in-block scan), then stream out
// in sorted order -> coalesced ~168B runs. NB=196/RB=256 geometry, R8's
// proven bfinal. 6 dispatches.

#define N_NODES 50000
#define N_EDGES 800000
#define IN_DIM  128
#define HID_DIM 64
#define OUT_DIM 64

#define RB   256                      // rows per bucket
#define NB   ((N_NODES + RB - 1) / RB)            // 196
#define EPB  4096                     // edges per bscatter block
#define NBLK_E ((N_EDGES + EPB - 1) / EPB)        // 196
#define BCAP 5120                     // padded bucket region; E=4081, 16sigma
#define GEMM1_GRID ((N_NODES + 31) / 32)          // 1563

typedef __attribute__((ext_vector_type(8))) short bf16x8;
typedef __attribute__((ext_vector_type(4))) float f32x4;

__device__ inline unsigned short f2bf(float x) {   // RNE fp32 -> bf16
    unsigned u = __float_as_uint(x);
    return (unsigned short)((u + 0x7FFFu + ((u >> 16) & 1u)) >> 16);
}
__device__ inline float bf2f(unsigned v) {
    return __uint_as_float(v << 16);
}

// ---------------- prep: weight transpose+bf16 convert, bcur zero ------
__global__ __launch_bounds__(256) void k_prep(
    const float* __restrict__ W1, unsigned short* __restrict__ Wt1,
    const float* __restrict__ W2, unsigned short* __restrict__ Wt2,
    int* __restrict__ bcur)
{
    int b = blockIdx.x, t = threadIdx.x;
    if (b < 32) {                       // IN_DIM*HID_DIM = 8192 = 32*256
        int e = b * 256 + t;
        int c = e / IN_DIM, k = e % IN_DIM;
        Wt1[c * IN_DIM + k] = f2bf(W1[k * HID_DIM + c]);
    } else if (b < 48) {                // HID_DIM*OUT_DIM = 4096 = 16*256
        int e2 = (b - 32) * 256 + t;
        int c = e2 / HID_DIM, k = e2 % HID_DIM;
        Wt2[c * HID_DIM + k] = f2bf(W2[k * OUT_DIM + c]);
    } else {
        if (t < NB) bcur[t] = 0;
    }
}

// ---------------- MFMA GEMM body (32 rows/block, 4 waves) -------------
// Both LDS tiles XOR-swizzled (byte ^= (row&7)<<4). Linear [N][64] bf16 out.
template <int K, bool IN_BF16>
__device__ __forceinline__ void gemm_body(
    unsigned short* __restrict__ Al, unsigned short* __restrict__ Bl,
    const void* __restrict__ Xv, const unsigned short* __restrict__ Wt,
    unsigned short* __restrict__ out, int bid, int t)
{
    int m0 = bid * 32;
    #pragma unroll
    for (int i = 0; i < K / 32; ++i) {
        int u4 = i * 256 + t;                 // uint4 index
        int col = (u4 * 8) / K, k = (u4 * 8) % K;
        uint4 w = ((const uint4*)Wt)[u4];
        int byte = (col * K + k) * 2;
        byte ^= ((col & 7) << 4);
        *(uint4*)((char*)Bl + byte) = w;
    }
    if (IN_BF16) {
        const unsigned short* X = (const unsigned short*)Xv;
        int row = t / (K / 8), k = (t % (K / 8)) * 8;
        int grow = m0 + row;
        uint4 v = make_uint4(0, 0, 0, 0);
        if (grow < N_NODES)
            v = *(const uint4*)(X + (size_t)grow * K + k);
        int byte = (row * K + k) * 2;
        byte ^= ((row & 7) << 4);
        *(uint4*)((char*)Al + byte) = v;
    } else {
        const float* X = (const float*)Xv;
        #pragma unroll
        for (int i = 0; i < K / 64; ++i) {
            int f8 = i * 256 + t;             // 8-float group
            int row = (f8 * 8) / K, k = (f8 * 8) % K;
            int grow = m0 + row;
            float4 xa = make_float4(0.f, 0.f, 0.f, 0.f), xb = xa;
            if (grow < N_NODES) {
                const float4* src = (const float4*)(X + (size_t)grow * K + k);
                xa = src[0];
                xb = src[1];
            }
            uint4 v;
            v.x = (unsigned)f2bf(xa.x) | ((unsigned)f2bf(xa.y) << 16);
            v.y = (unsigned)f2bf(xa.z) | ((unsigned)f2bf(xa.w) << 16);
            v.z = (unsigned)f2bf(xb.x) | ((unsigned)f2bf(xb.y) << 16);
            v.w = (unsigned)f2bf(xb.z) | ((unsigned)f2bf(xb.w) << 16);
            int byte = (row * K + k) * 2;
            byte ^= ((row & 7) << 4);
            *(uint4*)((char*)Al + byte) = v;
        }
    }
    __syncthreads();

    int w = t >> 6, l = t & 63;
    int lr0 = (w & 1) * 16;
    int c0  = (w >> 1) * 32;
    int lrow = lr0 + (l & 15);
    int kb = (l >> 4) * 8;
    int col0 = c0 + (l & 15), col1 = col0 + 16;
    f32x4 acc0 = {0.f, 0.f, 0.f, 0.f}, acc1 = {0.f, 0.f, 0.f, 0.f};
    #pragma unroll
    for (int kc = 0; kc < K / 32; ++kc) {
        int ka = kc * 32 + kb;
        int ab = (lrow * K + ka) * 2;  ab ^= ((lrow & 7) << 4);
        int bb0 = (col0 * K + ka) * 2; bb0 ^= ((col0 & 7) << 4);
        int bb1 = (col1 * K + ka) * 2; bb1 ^= ((col1 & 7) << 4);
        bf16x8 a  = *(const bf16x8*)((const char*)Al + ab);
        bf16x8 b0 = *(const bf16x8*)((const char*)Bl + bb0);
        bf16x8 b1 = *(const bf16x8*)((const char*)Bl + bb1);
        acc0 = __builtin_amdgcn_mfma_f32_16x16x32_bf16(a, b0, acc0, 0, 0, 0);
        acc1 = __builtin_amdgcn_mfma_f32_16x16x32_bf16(a, b1, acc1, 0, 0, 0);
    }
    int grow0 = m0 + lr0 + (l >> 4) * 4;
    #pragma unroll
    for (int j = 0; j < 4; ++j) {
        int gr = grow0 + j;
        if (gr < N_NODES) {
            out[(size_t)gr * 64 + col0] = f2bf(acc0[j]);
            out[(size_t)gr * 64 + col1] = f2bf(acc1[j]);
        }
    }
}

// ---------------- mega1: GEMM1 (blocks < GEMM1_GRID) || bscatter ------
// bscatter v2: rank -> in-block scan -> LDS bucket-sort -> coalesced
// streaming writeout (~168B runs instead of 64 scattered 8B per wave-store).
// smem layout: sbuf 0..32767 (4096 uint2) | lc @32768 (196) |
// scr @33568 (256 ints, scan scratch -> becomes lsc) | lbase @34592 (196).
__global__ __launch_bounds__(256) void k_mega1(
    const float* __restrict__ X, const unsigned short* __restrict__ Wt1,
    unsigned short* __restrict__ support,
    const int* __restrict__ erow, const int* __restrict__ ecol,
    const float* __restrict__ eval_, int* __restrict__ bcur,
    uint2* __restrict__ bucketed)
{
    __shared__ __align__(16) unsigned char smem[35392];
    int t = threadIdx.x;
    if (blockIdx.x < GEMM1_GRID) {
        gemm_body<IN_DIM, false>((unsigned short*)smem,
                                 (unsigned short*)(smem + 8192),
                                 X, Wt1, support, blockIdx.x, t);
        return;
    }
    uint2* sbuf  = (uint2*)smem;
    int*   lc    = (int*)(smem + 32768);
    int*   scr   = (int*)(smem + 33568);
    int*   lbase = (int*)(smem + 34592);
    int blk = blockIdx.x - GEMM1_GRID;
    if (t < NB) lc[t] = 0;
    __syncthreads();
    int base = blk * EPB;
    int ne_total = min(EPB, N_EDGES - base);
    int bkt[16], rnk[16];
    unsigned w0v[16], vv[16];
    #pragma unroll 4
    for (int i = 0; i < 16; ++i) {
        int e = base + i * 256 + t;
        bkt[i] = -1;
        if (e < N_EDGES) {
            unsigned r = (unsigned)erow[e];
            bkt[i] = (int)(r >> 8);
            w0v[i] = (unsigned)ecol[e] | ((r & 255u) << 16)
                     | ((unsigned)(r >> 8) << 24);
            vv[i] = __float_as_uint(eval_[e]);
            rnk[i] = atomicAdd(&lc[bkt[i]], 1);
        }
    }
    __syncthreads();
    // in-block exclusive scan of lc[0..NB) via 256-wide Hillis-Steele
    int cnt = (t < NB) ? lc[t] : 0;
    scr[t] = cnt;
    __syncthreads();
    #pragma unroll
    for (int off = 1; off < 256; off <<= 1) {
        int add = (t >= off) ? scr[t - off] : 0;
        __syncthreads();
        scr[t] += add;
        __syncthreads();
    }
    int excl = scr[t] - cnt;
    __syncthreads();
    scr[t] = excl;                       // scr becomes lsc (bucket start in sbuf)
    if (t < NB) lbase[t] = cnt ? atomicAdd(&bcur[t], cnt) : 0;
    __syncthreads();
    // place edges sorted by bucket into sbuf
    #pragma unroll 4
    for (int i = 0; i < 16; ++i)
        if (bkt[i] >= 0)
            sbuf[scr[bkt[i]] + rnk[i]] = make_uint2(w0v[i], vv[i]);
    __syncthreads();
    // coalesced streaming writeout (sorted order -> run-contiguous addrs)
    #pragma unroll 4
    for (int i = 0; i < 16; ++i) {
        int idx = i * 256 + t;
        if (idx < ne_total) {
            uint2 p = sbuf[idx];
            int bk = (int)(p.x >> 24);
            bucketed[(size_t)bk * BCAP + lbase[bk] + (idx - scr[bk])] = p;
        }
    }
}

// ---------------- pass B: one block per 256-row bucket ----------------
// LDS-cache the bucket's edges; per-row count -> in-block scan ->
// offs2[row]=(start,end) -> row-sorted scatter into pairs.
__global__ __launch_bounds__(256) void k_bfinal(
    const int* __restrict__ bcur, const uint2* __restrict__ bucketed,
    uint2* __restrict__ pairs, int2* __restrict__ offs2)
{
    __shared__ uint2 ebuf[BCAP];        // 40 KB
    __shared__ int rcnt[256];
    __shared__ int rsc[256];
    int t = threadIdx.x, b = blockIdx.x;
    int ne = bcur[b];
    int base0 = b * BCAP;
    rcnt[t] = 0;
    __syncthreads();
    for (int i = t; i < ne; i += 256) {
        uint2 p = bucketed[(size_t)base0 + i];
        ebuf[i] = p;
        atomicAdd(&rcnt[(p.x >> 16) & 255], 1);
    }
    __syncthreads();
    int v = rcnt[t];
    rsc[t] = v;
    __syncthreads();
    #pragma unroll
    for (int off = 1; off < 256; off <<= 1) {
        int add = (t >= off) ? rsc[t - off] : 0;
        __syncthreads();
        rsc[t] += add;
        __syncthreads();
    }
    int start = base0 + rsc[t] - v;
    int gr = (b << 8) + t;
    if (gr < N_NODES) offs2[gr] = make_int2(start, start + v);
    rcnt[t] = start;                    // becomes row cursor
    __syncthreads();
    for (int i = t; i < ne; i += 256) {
        uint2 p = ebuf[i];
        int pos = atomicAdd(&rcnt[(p.x >> 16) & 255], 1);
        pairs[pos] = make_uint2(p.x & 0xFFFFu, p.y);
    }
}

// ---------------- gather SpMM: bf16 dense [N][64], 8-way unroll -------
template <bool APPLY_RELU, bool OUT_BF16>
__global__ __launch_bounds__(256) void k_gather(
    const int2* __restrict__ offs2, const uint2* __restrict__ pairs,
    const unsigned short* __restrict__ dense, const float* __restrict__ bias,
    void* __restrict__ outp)
{
    int t = threadIdx.x;
    int r = __builtin_amdgcn_readfirstlane(blockIdx.x * 4 + (t >> 6));
    int d = t & 63;
    int2 oe = offs2[r];
    int e0 = oe.x, e1 = oe.y;
    float a[8];
    a[0] = bias[d];
    #pragma unroll
    for (int i = 1; i < 8; ++i) a[i] = 0.f;
    int e = e0;
    for (; e + 8 <= e1; e += 8) {
        uint2 p[8];
        #pragma unroll
        for (int i = 0; i < 8; ++i) p[i] = pairs[e + i];
        unsigned v[8];
        #pragma unroll
        for (int i = 0; i < 8; ++i) v[i] = dense[(size_t)p[i].x * 64u + d];
        #pragma unroll
        for (int i = 0; i < 8; ++i)
            a[i] = fmaf(__uint_as_float(p[i].y), bf2f(v[i]), a[i]);
    }
    if (e + 4 <= e1) {
        uint2 p[4];
        #pragma unroll
        for (int i = 0; i < 4; ++i) p[i] = pairs[e + i];
        unsigned v[4];
        #pragma unroll
        for (int i = 0; i < 4; ++i) v[i] = dense[(size_t)p[i].x * 64u + d];
        #pragma unroll
        for (int i = 0; i < 4; ++i)
            a[i] = fmaf(__uint_as_float(p[i].y), bf2f(v[i]), a[i]);
        e += 4;
    }
    for (; e < e1; ++e) {
        uint2 p = pairs[e];
        a[0] = fmaf(__uint_as_float(p.y),
                    bf2f(dense[(size_t)p.x * 64u + d]), a[0]);
    }
    float acc = ((a[0] + a[1]) + (a[2] + a[3])) +
                ((a[4] + a[5]) + (a[6] + a[7]));
    if (APPLY_RELU) acc = fmaxf(acc, 0.f);
    if (OUT_BF16)
        ((unsigned short*)outp)[(size_t)r * 64 + d] = f2bf(acc);
    else
        ((float*)outp)[(size_t)r * 64 + d] = acc;
}

// ---------------- GEMM2 standalone (K=64, bf16 in) --------------------
__global__ __launch_bounds__(256) void k_gemm2(
    const unsigned short* __restrict__ X, const unsigned short* __restrict__ Wt,
    unsigned short* __restrict__ out)
{
    __shared__ unsigned short Al[32 * HID_DIM];
    __shared__ unsigned short Bl[64 * HID_DIM];
    gemm_body<HID_DIM, true>(Al, Bl, X, Wt, out, blockIdx.x, threadIdx.x);
}

extern "C" void kernel_launch(void* const* d_in, const int* in_sizes, int n_in,
                              void* d_out, int out_size, void* d_ws, size_t ws_size,
                              hipStream_t stream)
{
    const float* x     = (const float*)d_in[0];
    const int*   erow  = (const int*)d_in[1];
    const int*   ecol  = (const int*)d_in[2];
    const float* eval_ = (const float*)d_in[3];
    const float* W1    = (const float*)d_in[4];
    const float* b1    = (const float*)d_in[5];
    const float* W2    = (const float*)d_in[6];
    const float* b2    = (const float*)d_in[7];
    float* out = (float*)d_out;

    // ws (~30 MB): pairs 8.03MB | bucketed 8.03MB | support bf16 6.4MB |
    // agg1 bf16 6.4MB | Wt1 | Wt2 | bcur | offs2
    uint2* pairs    = (uint2*)d_ws;
    uint2* bucketed = pairs + (size_t)NB * BCAP;
    unsigned short* support = (unsigned short*)(bucketed + (size_t)NB * BCAP);
    unsigned short* agg1 = support + (size_t)N_NODES * 64;
    unsigned short* Wt1 = agg1 + (size_t)N_NODES * 64;
    unsigned short* Wt2 = Wt1 + IN_DIM * HID_DIM;
    int*  bcur  = (int*)(Wt2 + HID_DIM * OUT_DIM);
    int2* offs2 = (int2*)(bcur + NB);          // NB=196 even -> 8B-aligned

    const int row_grid = N_NODES / 4;          // 12500 (gather)

    // 6 dispatches
    k_prep<<<49, 256, 0, stream>>>(W1, Wt1, W2, Wt2, bcur);
    k_mega1<<<GEMM1_GRID + NBLK_E, 256, 0, stream>>>(
        x, Wt1, support, erow, ecol, eval_, bcur, bucketed);
    k_bfinal<<<NB, 256, 0, stream>>>(bcur, bucketed, pairs, offs2);
    k_gather<true, true><<<row_grid, 256, 0, stream>>>(
        offs2, pairs, support, b1, agg1);
    k_gemm2<<<GEMM1_GRID, 256, 0, stream>>>(agg1, Wt2, support);
    k_gather<false, false><<<row_grid, 256, 0, stream>>>(
        offs2, pairs, support, b2, out);
}